// Round 1
// baseline (664.435 us; speedup 1.0000x reference)
//
#include <hip/hip_runtime.h>
#include <math.h>

// Problem dims (fixed by reference)
constexpr int cB = 8, cH = 512, cL = 4096, cN = 32;
constexpr int cG = 32, cLC = 128;            // 32 chunks of 128 along L
constexpr int cHN = cH * cN;                 // 16384

// Workspace layout (float offsets)
constexpr size_t OF_RR  = 0;                 // r real            [HN]
constexpr size_t OF_RI  = (size_t)cHN;       // r imag            [HN]
constexpr size_t OF_RPR = (size_t)2*cHN;     // r^128 real        [HN]
constexpr size_t OF_RPI = (size_t)3*cHN;     // r^128 imag        [HN]
constexpr size_t OF_C2R = (size_t)4*cHN;     // 2*Cs real         [HN]
constexpr size_t OF_C2I = (size_t)5*cHN;     // 2*Cs imag         [HN]
constexpr size_t OF_S   = (size_t)6*cHN;     // chunk states/inits: B*H*G*N complex
constexpr size_t OF_G   = OF_S + (size_t)cB*cH*cG*cN*2;  // g = gelu(y+u*D): B*H*L floats
// total floats: 98304 + 8388608 + 16777216 = 25264128 (~96.4 MB)

// ---------------- K0: per-(h,n) constants ----------------
__global__ void k_consts(const float* __restrict__ log_dt,
                         const float* __restrict__ log_A_real,
                         const float* __restrict__ A_imag,
                         const float* __restrict__ Cin,
                         float* __restrict__ ws)
{
    int tid = blockIdx.x * 256 + threadIdx.x;
    if (tid >= cHN) return;
    int h = tid >> 5;
    float dt = expf(log_dt[h]);
    float Ar = -expf(log_A_real[tid]);
    float Ai = A_imag[tid];
    float dr = dt * Ar, di = dt * Ai;
    float er = expf(dr);
    float rr = er * cosf(di), ri = er * sinf(di);
    // r^LC for the chunk scan (computed via exp for accuracy)
    float erL = expf(dr * (float)cLC);
    float diL = di * (float)cLC;
    float rpr = erL * cosf(diL), rpi = erL * sinf(diL);
    // Cs = C * (r - 1) / A ; store 2*Cs
    float cr = Cin[2*tid], ci = Cin[2*tid+1];
    float nr = rr - 1.0f, ni = ri;
    float inv = 1.0f / (Ar*Ar + Ai*Ai);
    float wr = (nr*Ar + ni*Ai) * inv;
    float wi = (ni*Ar - nr*Ai) * inv;
    float csr = cr*wr - ci*wi;
    float csi = cr*wi + ci*wr;
    ws[OF_RR  + tid] = rr;  ws[OF_RI  + tid] = ri;
    ws[OF_RPR + tid] = rpr; ws[OF_RPI + tid] = rpi;
    ws[OF_C2R + tid] = 2.0f*csr; ws[OF_C2I + tid] = 2.0f*csi;
}

// ---------------- K1: chunk states (zero-init recurrence) ----------------
__global__ __launch_bounds__(256) void k_chunk_state(const float* __restrict__ u,
                                                     float* __restrict__ ws)
{
    int gid = blockIdx.x * 256 + threadIdx.x;   // B*H*G = 131072 threads
    int c  = gid & (cG - 1);
    int bh = gid >> 5;
    int h  = bh & (cH - 1);
    float rrv[cN], riv[cN];
    const float* crr = ws + OF_RR + (size_t)h * cN;
    const float* cri = ws + OF_RI + (size_t)h * cN;
    #pragma unroll
    for (int n = 0; n < cN; ++n) { rrv[n] = crr[n]; riv[n] = cri[n]; }
    float xr[cN], xi[cN];
    #pragma unroll
    for (int n = 0; n < cN; ++n) { xr[n] = 0.f; xi[n] = 0.f; }
    const float* up = u + (size_t)bh * cL + (size_t)c * cLC;
    for (int i0 = 0; i0 < cLC; i0 += 4) {
        float4 uv = *(const float4*)&up[i0];
        float us[4] = {uv.x, uv.y, uv.z, uv.w};
        #pragma unroll
        for (int s = 0; s < 4; ++s) {
            float uu = us[s];
            #pragma unroll
            for (int n = 0; n < cN; ++n) {
                float nxr = fmaf(rrv[n], xr[n], fmaf(-riv[n], xi[n], uu));
                float nxi = fmaf(rrv[n], xi[n], riv[n] * xr[n]);
                xr[n] = nxr; xi[n] = nxi;
            }
        }
    }
    // store s: layout [(bh*G + c)*N + n] as complex
    float* sp = ws + OF_S + ((size_t)(bh * cG + c) * cN) * 2;
    #pragma unroll
    for (int q = 0; q < cN/2; ++q) {
        float4 v = make_float4(xr[2*q], xi[2*q], xr[2*q+1], xi[2*q+1]);
        *(float4*)&sp[4*q] = v;
    }
}

// ---------------- K2: scan across chunks, in-place s -> per-chunk init state ----------------
__global__ __launch_bounds__(256) void k_scan(float* __restrict__ ws)
{
    int tid = blockIdx.x * 256 + threadIdx.x;   // B*H*N = 131072 threads
    int n  = tid & (cN - 1);
    int bh = tid >> 5;
    int h  = bh & (cH - 1);
    float rpr = ws[OF_RPR + (size_t)h * cN + n];
    float rpi = ws[OF_RPI + (size_t)h * cN + n];
    float Xr = 0.f, Xi = 0.f;
    float* sp = ws + OF_S + ((size_t)bh * cG * cN + n) * 2;
    for (int c = 0; c < cG; ++c) {
        size_t idx = (size_t)c * cN * 2;
        float sr = sp[idx], si = sp[idx + 1];
        sp[idx] = Xr; sp[idx + 1] = Xi;          // init state for chunk c = X_{c-1}
        float nXr = fmaf(rpr, Xr, fmaf(-rpi, Xi, sr));
        float nXi = fmaf(rpr, Xi, fmaf(rpi, Xr, si));
        Xr = nXr; Xi = nXi;
    }
}

// ---------------- K3: recurrence with init + y + D-skip + exact GELU -> g ----------------
__global__ __launch_bounds__(256) void k_recur(const float* __restrict__ u,
                                               const float* __restrict__ Dvec,
                                               float* __restrict__ ws)
{
    int gid = blockIdx.x * 256 + threadIdx.x;   // B*H*G threads
    int c  = gid & (cG - 1);
    int bh = gid >> 5;
    int h  = bh & (cH - 1);
    float rrv[cN], riv[cN], c2r[cN], c2i[cN];
    {
        const float* p0 = ws + OF_RR  + (size_t)h * cN;
        const float* p1 = ws + OF_RI  + (size_t)h * cN;
        const float* p2 = ws + OF_C2R + (size_t)h * cN;
        const float* p3 = ws + OF_C2I + (size_t)h * cN;
        #pragma unroll
        for (int n = 0; n < cN; ++n) { rrv[n]=p0[n]; riv[n]=p1[n]; c2r[n]=p2[n]; c2i[n]=p3[n]; }
    }
    float xr[cN], xi[cN];
    const float* ip = ws + OF_S + ((size_t)(bh * cG + c) * cN) * 2;
    #pragma unroll
    for (int q = 0; q < cN/2; ++q) {
        float4 v = *(const float4*)&ip[4*q];
        xr[2*q] = v.x; xi[2*q] = v.y; xr[2*q+1] = v.z; xi[2*q+1] = v.w;
    }
    float Dh = Dvec[h];
    const float* up = u + (size_t)bh * cL + (size_t)c * cLC;
    float* gp = ws + OF_G + (size_t)bh * cL + (size_t)c * cLC;

    auto step = [&](float uu) -> float {
        float yacc = 0.f;
        #pragma unroll
        for (int n = 0; n < cN; ++n) {
            float nxr = fmaf(rrv[n], xr[n], fmaf(-riv[n], xi[n], uu));
            float nxi = fmaf(rrv[n], xi[n], riv[n] * xr[n]);
            xr[n] = nxr; xi[n] = nxi;
            yacc = fmaf(c2r[n], nxr, yacc);
            yacc = fmaf(-c2i[n], nxi, yacc);
        }
        float v = fmaf(uu, Dh, yacc);
        return 0.5f * v * (1.0f + erff(v * 0.70710678118654752f));
    };

    for (int i0 = 0; i0 < cLC; i0 += 4) {
        float4 uv = *(const float4*)&up[i0];
        float4 gv;
        gv.x = step(uv.x);
        gv.y = step(uv.y);
        gv.z = step(uv.z);
        gv.w = step(uv.w);
        *(float4*)&gp[i0] = gv;
    }
}

// ---------------- K4: fused 1x1-conv GEMM + bias + GLU ----------------
// Block computes a 64-row (a) + paired 64-row (b, offset +512) x 128-col tile.
__global__ __launch_bounds__(256) void k_gemm_glu(const float* __restrict__ W,
                                                  const float* __restrict__ bias,
                                                  const float* __restrict__ g,
                                                  float* __restrict__ out)
{
    __shared__ float As[16][132];   // [k][row]: rows 0..63 = a-rows, 64..127 = b-rows
    __shared__ float Bs[16][132];   // [k][col]
    const int t  = threadIdx.x;
    const int tx = t & 15;          // col group: cols tx*4..+4 and 64+tx*4..+4
    const int ty = t >> 4;          // row group: rows ty*4..+4
    const int l0 = blockIdx.x * 128;
    const int r0 = blockIdx.y * 64;
    const int b  = blockIdx.z;
    const float* gb = g + (size_t)b * cH * cL;
    float acc_a[4][8], acc_b[4][8];
    #pragma unroll
    for (int i = 0; i < 4; ++i)
        #pragma unroll
        for (int j = 0; j < 8; ++j) { acc_a[i][j] = 0.f; acc_b[i][j] = 0.f; }

    const int arow = t >> 2;            // 0..63
    const int akc  = (t & 3) << 2;      // 0,4,8,12

    for (int k0 = 0; k0 < cH; k0 += 16) {
        float4 va = *(const float4*)&W[(size_t)(r0 + arow) * cH + k0 + akc];
        float4 vb = *(const float4*)&W[(size_t)(512 + r0 + arow) * cH + k0 + akc];
        int i1 = t, i2 = t + 256;
        float4 v1 = *(const float4*)&gb[(size_t)(k0 + (i1 >> 5)) * cL + l0 + ((i1 & 31) << 2)];
        float4 v2 = *(const float4*)&gb[(size_t)(k0 + (i2 >> 5)) * cL + l0 + ((i2 & 31) << 2)];
        __syncthreads();   // previous tile's LDS reads complete
        As[akc+0][arow] = va.x; As[akc+1][arow] = va.y;
        As[akc+2][arow] = va.z; As[akc+3][arow] = va.w;
        As[akc+0][64+arow] = vb.x; As[akc+1][64+arow] = vb.y;
        As[akc+2][64+arow] = vb.z; As[akc+3][64+arow] = vb.w;
        *(float4*)&Bs[i1 >> 5][(i1 & 31) << 2] = v1;
        *(float4*)&Bs[i2 >> 5][(i2 & 31) << 2] = v2;
        __syncthreads();
        #pragma unroll
        for (int k = 0; k < 16; ++k) {
            float4 a1 = *(const float4*)&As[k][ty*4];
            float4 a2 = *(const float4*)&As[k][64 + ty*4];
            float4 b1 = *(const float4*)&Bs[k][tx*4];
            float4 b2 = *(const float4*)&Bs[k][64 + tx*4];
            float av1[4] = {a1.x, a1.y, a1.z, a1.w};
            float av2[4] = {a2.x, a2.y, a2.z, a2.w};
            float bv[8]  = {b1.x, b1.y, b1.z, b1.w, b2.x, b2.y, b2.z, b2.w};
            #pragma unroll
            for (int i = 0; i < 4; ++i)
                #pragma unroll
                for (int j = 0; j < 8; ++j) {
                    acc_a[i][j] = fmaf(av1[i], bv[j], acc_a[i][j]);
                    acc_b[i][j] = fmaf(av2[i], bv[j], acc_b[i][j]);
                }
        }
    }
    // epilogue: bias + GLU (a * sigmoid(b)), rows pair (o, o+512)
    #pragma unroll
    for (int i = 0; i < 4; ++i) {
        int o = r0 + ty*4 + i;
        float ba = bias[o], bb = bias[512 + o];
        float4 ra, rb;
        {
            float a0 = acc_a[i][0] + ba, a1 = acc_a[i][1] + ba, a2 = acc_a[i][2] + ba, a3 = acc_a[i][3] + ba;
            float g0 = acc_b[i][0] + bb, g1 = acc_b[i][1] + bb, g2 = acc_b[i][2] + bb, g3 = acc_b[i][3] + bb;
            ra.x = a0 / (1.f + expf(-g0)); ra.y = a1 / (1.f + expf(-g1));
            ra.z = a2 / (1.f + expf(-g2)); ra.w = a3 / (1.f + expf(-g3));
        }
        {
            float a0 = acc_a[i][4] + ba, a1 = acc_a[i][5] + ba, a2 = acc_a[i][6] + ba, a3 = acc_a[i][7] + ba;
            float g0 = acc_b[i][4] + bb, g1 = acc_b[i][5] + bb, g2 = acc_b[i][6] + bb, g3 = acc_b[i][7] + bb;
            rb.x = a0 / (1.f + expf(-g0)); rb.y = a1 / (1.f + expf(-g1));
            rb.z = a2 / (1.f + expf(-g2)); rb.w = a3 / (1.f + expf(-g3));
        }
        float* op = out + ((size_t)b * cH + o) * cL + l0;
        *(float4*)&op[tx*4]      = ra;
        *(float4*)&op[64 + tx*4] = rb;
    }
}

extern "C" void kernel_launch(void* const* d_in, const int* in_sizes, int n_in,
                              void* d_out, int out_size, void* d_ws, size_t ws_size,
                              hipStream_t stream)
{
    (void)in_sizes; (void)n_in; (void)out_size; (void)ws_size;
    const float* u          = (const float*)d_in[0];
    const float* log_dt     = (const float*)d_in[1];
    const float* log_A_real = (const float*)d_in[2];
    const float* A_imag     = (const float*)d_in[3];
    const float* C          = (const float*)d_in[4];
    const float* D          = (const float*)d_in[5];
    const float* W          = (const float*)d_in[6];
    const float* bias       = (const float*)d_in[7];
    float* out = (float*)d_out;
    float* ws  = (float*)d_ws;

    hipLaunchKernelGGL(k_consts, dim3(cHN / 256), dim3(256), 0, stream,
                       log_dt, log_A_real, A_imag, C, ws);
    hipLaunchKernelGGL(k_chunk_state, dim3(cB * cH * cG / 256), dim3(256), 0, stream, u, ws);
    hipLaunchKernelGGL(k_scan, dim3(cB * cH * cN / 256), dim3(256), 0, stream, ws);
    hipLaunchKernelGGL(k_recur, dim3(cB * cH * cG / 256), dim3(256), 0, stream, u, D, ws);
    hipLaunchKernelGGL(k_gemm_glu, dim3(cL / 128, cH / 64, cB), dim3(256), 0, stream,
                       W, bias, ws + OF_G, out);
}

// Round 2
// 348.822 us; speedup vs baseline: 1.9048x; 1.9048x over previous
//
#include <hip/hip_runtime.h>
#include <math.h>

// Problem dims (fixed by reference)
constexpr int cB = 8, cH = 512, cL = 4096, cN = 32;
constexpr int cG = 32, cLC = 128;            // 32 chunks of 128 along L
constexpr int cHN = cH * cN;                 // 16384

// Workspace layout (float offsets)
constexpr size_t OF_RR  = 0;                 // r real            [HN]
constexpr size_t OF_RI  = (size_t)cHN;       // r imag            [HN]
constexpr size_t OF_RPR = (size_t)2*cHN;     // r^128 real        [HN]
constexpr size_t OF_RPI = (size_t)3*cHN;     // r^128 imag        [HN]
constexpr size_t OF_C2R = (size_t)4*cHN;     // 2*Cs real         [HN]
constexpr size_t OF_C2I = (size_t)5*cHN;     // 2*Cs imag         [HN]
constexpr size_t OF_S   = (size_t)6*cHN;     // chunk states/inits: B*H*G*N complex
constexpr size_t OF_WP  = OF_S + (size_t)cB*cH*cG*cN*2;   // packed bf16 W: 1024*512 ushort
constexpr size_t OF_G   = OF_WP + (size_t)1024*512/2;     // bf16 g: B*H*L ushort
// total floats: 98304 + 8388608 + 262144 + 8388608 = 17137664 (~65.4 MB)

typedef __bf16 bf16x8 __attribute__((ext_vector_type(8)));
typedef float  f32x4  __attribute__((ext_vector_type(4)));

static __device__ __forceinline__ ushort f2bf(float x) {
    unsigned u = __float_as_uint(x);
    unsigned r = (u + 0x7fffu + ((u >> 16) & 1u)) >> 16;   // RNE
    return (ushort)r;
}

// ---------------- K0: per-(h,n) constants ----------------
__global__ void k_consts(const float* __restrict__ log_dt,
                         const float* __restrict__ log_A_real,
                         const float* __restrict__ A_imag,
                         const float* __restrict__ Cin,
                         float* __restrict__ ws)
{
    int tid = blockIdx.x * 256 + threadIdx.x;
    if (tid >= cHN) return;
    int h = tid >> 5;
    float dt = expf(log_dt[h]);
    float Ar = -expf(log_A_real[tid]);
    float Ai = A_imag[tid];
    float dr = dt * Ar, di = dt * Ai;
    float er = expf(dr);
    float rr = er * cosf(di), ri = er * sinf(di);
    float erL = expf(dr * (float)cLC);
    float diL = di * (float)cLC;
    float rpr = erL * cosf(diL), rpi = erL * sinf(diL);
    float cr = Cin[2*tid], ci = Cin[2*tid+1];
    float nr = rr - 1.0f, ni = ri;
    float inv = 1.0f / (Ar*Ar + Ai*Ai);
    float wr = (nr*Ar + ni*Ai) * inv;
    float wi = (ni*Ar - nr*Ai) * inv;
    float csr = cr*wr - ci*wi;
    float csi = cr*wi + ci*wr;
    ws[OF_RR  + tid] = rr;  ws[OF_RI  + tid] = ri;
    ws[OF_RPR + tid] = rpr; ws[OF_RPI + tid] = rpi;
    ws[OF_C2R + tid] = 2.0f*csr; ws[OF_C2I + tid] = 2.0f*csi;
}

// ---------------- K0b: pack W (fp32 [1024][512]) -> bf16 with GLU row interleave ----------------
__global__ void k_pack_w(const float* __restrict__ W, ushort* __restrict__ Wp)
{
    int idx = blockIdx.x * 256 + threadIdx.x;   // one per 4 elements
    int base = idx * 4;                          // over 1024*512
    int m = base >> 9;
    int k = base & 511;
    int src = (m & 1) ? (512 + (m >> 1)) : (m >> 1);
    float4 v = *(const float4*)&W[(size_t)src * 512 + k];
    ushort4 o;
    o.x = f2bf(v.x); o.y = f2bf(v.y); o.z = f2bf(v.z); o.w = f2bf(v.w);
    *(ushort4*)&Wp[base] = o;
}

// ---------------- K1: chunk states (zero-init recurrence) ----------------
__global__ __launch_bounds__(256) void k_chunk_state(const float* __restrict__ u,
                                                     float* __restrict__ ws)
{
    int gid = blockIdx.x * 256 + threadIdx.x;   // B*H*G = 131072 threads
    int c  = gid & (cG - 1);
    int bh = gid >> 5;
    int h  = bh & (cH - 1);
    float rrv[cN], riv[cN];
    const float* crr = ws + OF_RR + (size_t)h * cN;
    const float* cri = ws + OF_RI + (size_t)h * cN;
    #pragma unroll
    for (int n = 0; n < cN; ++n) { rrv[n] = crr[n]; riv[n] = cri[n]; }
    float xr[cN], xi[cN];
    #pragma unroll
    for (int n = 0; n < cN; ++n) { xr[n] = 0.f; xi[n] = 0.f; }
    const float* up = u + (size_t)bh * cL + (size_t)c * cLC;
    for (int i0 = 0; i0 < cLC; i0 += 4) {
        float4 uv = *(const float4*)&up[i0];
        float us[4] = {uv.x, uv.y, uv.z, uv.w};
        #pragma unroll
        for (int s = 0; s < 4; ++s) {
            float uu = us[s];
            #pragma unroll
            for (int n = 0; n < cN; ++n) {
                float nxr = fmaf(rrv[n], xr[n], fmaf(-riv[n], xi[n], uu));
                float nxi = fmaf(rrv[n], xi[n], riv[n] * xr[n]);
                xr[n] = nxr; xi[n] = nxi;
            }
        }
    }
    float* sp = ws + OF_S + ((size_t)(bh * cG + c) * cN) * 2;
    #pragma unroll
    for (int q = 0; q < cN/2; ++q) {
        float4 v = make_float4(xr[2*q], xi[2*q], xr[2*q+1], xi[2*q+1]);
        *(float4*)&sp[4*q] = v;
    }
}

// ---------------- K2: scan across chunks, in-place s -> per-chunk init state ----------------
__global__ __launch_bounds__(256) void k_scan(float* __restrict__ ws)
{
    int tid = blockIdx.x * 256 + threadIdx.x;   // B*H*N = 131072 threads
    int n  = tid & (cN - 1);
    int bh = tid >> 5;
    int h  = bh & (cH - 1);
    float rpr = ws[OF_RPR + (size_t)h * cN + n];
    float rpi = ws[OF_RPI + (size_t)h * cN + n];
    float Xr = 0.f, Xi = 0.f;
    float* sp = ws + OF_S + ((size_t)bh * cG * cN + n) * 2;
    for (int c = 0; c < cG; ++c) {
        size_t idx = (size_t)c * cN * 2;
        float sr = sp[idx], si = sp[idx + 1];
        sp[idx] = Xr; sp[idx + 1] = Xi;
        float nXr = fmaf(rpr, Xr, fmaf(-rpi, Xi, sr));
        float nXi = fmaf(rpr, Xi, fmaf(rpi, Xr, si));
        Xr = nXr; Xi = nXi;
    }
}

// ---------------- K3: recurrence with init + y + D-skip + exact GELU -> g (bf16) ----------------
__global__ __launch_bounds__(256) void k_recur(const float* __restrict__ u,
                                               const float* __restrict__ Dvec,
                                               float* __restrict__ ws)
{
    int gid = blockIdx.x * 256 + threadIdx.x;   // B*H*G threads
    int c  = gid & (cG - 1);
    int bh = gid >> 5;
    int h  = bh & (cH - 1);
    float rrv[cN], riv[cN], c2r[cN], c2i[cN];
    {
        const float* p0 = ws + OF_RR  + (size_t)h * cN;
        const float* p1 = ws + OF_RI  + (size_t)h * cN;
        const float* p2 = ws + OF_C2R + (size_t)h * cN;
        const float* p3 = ws + OF_C2I + (size_t)h * cN;
        #pragma unroll
        for (int n = 0; n < cN; ++n) { rrv[n]=p0[n]; riv[n]=p1[n]; c2r[n]=p2[n]; c2i[n]=p3[n]; }
    }
    float xr[cN], xi[cN];
    const float* ip = ws + OF_S + ((size_t)(bh * cG + c) * cN) * 2;
    #pragma unroll
    for (int q = 0; q < cN/2; ++q) {
        float4 v = *(const float4*)&ip[4*q];
        xr[2*q] = v.x; xi[2*q] = v.y; xr[2*q+1] = v.z; xi[2*q+1] = v.w;
    }
    float Dh = Dvec[h];
    const float* up = u + (size_t)bh * cL + (size_t)c * cLC;
    ushort* gp = (ushort*)(ws + OF_G) + (size_t)bh * cL + (size_t)c * cLC;

    auto step = [&](float uu) -> float {
        float yacc = 0.f;
        #pragma unroll
        for (int n = 0; n < cN; ++n) {
            float nxr = fmaf(rrv[n], xr[n], fmaf(-riv[n], xi[n], uu));
            float nxi = fmaf(rrv[n], xi[n], riv[n] * xr[n]);
            xr[n] = nxr; xi[n] = nxi;
            yacc = fmaf(c2r[n], nxr, yacc);
            yacc = fmaf(-c2i[n], nxi, yacc);
        }
        float v = fmaf(uu, Dh, yacc);
        return 0.5f * v * (1.0f + erff(v * 0.70710678118654752f));
    };

    for (int i0 = 0; i0 < cLC; i0 += 4) {
        float4 uv = *(const float4*)&up[i0];
        ushort4 gv;
        gv.x = f2bf(step(uv.x));
        gv.y = f2bf(step(uv.y));
        gv.z = f2bf(step(uv.z));
        gv.w = f2bf(step(uv.w));
        *(ushort4*)&gp[i0] = gv;
    }
}

// ---------------- K4: MFMA GEMM + bias + GLU ----------------
// C[o,l] = sum_k Wp[m,k] * g[b,k,l]; packed rows m=2i (a=W[i]), m=2i+1 (b=W[i+512]).
// Block: 128 packed rows x 128 cols. 4 waves in 2x2, each 64x64 (4x4 frags of 16x16x32).
constexpr int BK = 32, LDK = 40;   // LDS row stride (bf16): 80B = 20 banks, 2-way-free b128
__global__ __launch_bounds__(256) void k_gemm_mfma(const ushort* __restrict__ Wp,
                                                   const float* __restrict__ bias,
                                                   const ushort* __restrict__ gbf,
                                                   float* __restrict__ out)
{
    __shared__ ushort As[128 * LDK];
    __shared__ ushort Bs[128 * LDK];
    const int t    = threadIdx.x;
    const int l0   = blockIdx.x * 128;
    const int by   = blockIdx.y;       // Wp rows [128*by, +128) -> out rows [64*by, +64)
    const int b    = blockIdx.z;
    const int wave = t >> 6, lane = t & 63;
    const int wm   = wave & 1, wn = wave >> 1;
    const int lm   = lane & 15, q = lane >> 4;

    // A staging: thread covers row (t&127), k-chunk 16*(t>>7) .. +16
    const int arow = t & 127;
    const int ah   = t >> 7;
    // B staging: thread covers l = l0+8*lq .. +8, k rows 2*kp, 2*kp+1
    const int lq = t & 15, kp = t >> 4;
    const int ko = kp >> 2;            // k-octet of this thread's pair
    const int kr = (2 * kp) & 7;       // within-octet offset

    const ushort* gB = gbf + (size_t)b * ((size_t)cH * cL);
    const ushort* wRow = Wp + (size_t)(by * 128 + arow) * 512 + ah * 16;

    f32x4 acc[4][4];
    #pragma unroll
    for (int i = 0; i < 4; ++i)
        #pragma unroll
        for (int j = 0; j < 4; ++j)
            acc[i][j] = (f32x4){0.f, 0.f, 0.f, 0.f};

    for (int k0 = 0; k0 < cH; k0 += BK) {
        // global loads
        uint4 wa0 = *(const uint4*)&wRow[k0];
        uint4 wa1 = *(const uint4*)&wRow[k0 + 8];
        uint4 g0  = *(const uint4*)&gB[(size_t)(k0 + 2*kp)     * cL + l0 + 8*lq];
        uint4 g1  = *(const uint4*)&gB[(size_t)(k0 + 2*kp + 1) * cL + l0 + 8*lq];
        __syncthreads();                       // prior tile's LDS reads done
        // A: [row][k] direct, b128 writes
        *(uint4*)&As[arow * LDK + 16*ah]     = wa0;
        *(uint4*)&As[arow * LDK + 16*ah + 8] = wa1;
        // B: transpose-interleave: Bs[l][k] with octet swizzle ko' = ko ^ ((l>>3)&3)
        {
            unsigned ua[4] = {g0.x, g0.y, g0.z, g0.w};
            unsigned ub[4] = {g1.x, g1.y, g1.z, g1.w};
            #pragma unroll
            for (int e = 0; e < 4; ++e) {
                unsigned w0 = (ua[e] & 0xffffu) | (ub[e] << 16);
                unsigned w1 = (ua[e] >> 16)     | (ub[e] & 0xffff0000u);
                int lr0 = 8*lq + 2*e;
                int c0  = ((ko ^ (lq & 3)) << 3) + kr;   // (lr>>3)&3 == lq&3
                *(unsigned*)&Bs[lr0 * LDK + c0]       = w0;
                *(unsigned*)&Bs[(lr0 + 1) * LDK + c0] = w1;
            }
        }
        __syncthreads();
        // fragments
        bf16x8 af[4], bf[4];
        #pragma unroll
        for (int mi = 0; mi < 4; ++mi) {
            int row = 64*wm + 16*mi + lm;
            af[mi] = *(const bf16x8*)&As[row * LDK + (q << 3)];
        }
        #pragma unroll
        for (int ni = 0; ni < 4; ++ni) {
            int row = 64*wn + 16*ni + lm;
            int kx  = (row >> 3) & 3;
            bf[ni] = *(const bf16x8*)&Bs[row * LDK + ((q ^ kx) << 3)];
        }
        #pragma unroll
        for (int mi = 0; mi < 4; ++mi)
            #pragma unroll
            for (int ni = 0; ni < 4; ++ni)
                acc[mi][ni] = __builtin_amdgcn_mfma_f32_16x16x32_bf16(af[mi], bf[ni], acc[mi][ni], 0, 0, 0);
    }

    // epilogue: rows pair (reg 2p, 2p+1) = (a,b) in-lane; o = 64*by + 32*wm + 8*mi + 2*q + p
    const int obase = by * 64 + 32 * wm;
    #pragma unroll
    for (int mi = 0; mi < 4; ++mi) {
        #pragma unroll
        for (int p = 0; p < 2; ++p) {
            int o = obase + 8*mi + 2*q + p;
            float ba = bias[o], bb = bias[512 + o];
            float* orow = out + ((size_t)b * cH + o) * cL + l0 + 64*wn + lm;
            #pragma unroll
            for (int ni = 0; ni < 4; ++ni) {
                float av = acc[mi][ni][2*p]     + ba;
                float gv = acc[mi][ni][2*p + 1] + bb;
                orow[16 * ni] = av / (1.f + expf(-gv));
            }
        }
    }
}

extern "C" void kernel_launch(void* const* d_in, const int* in_sizes, int n_in,
                              void* d_out, int out_size, void* d_ws, size_t ws_size,
                              hipStream_t stream)
{
    (void)in_sizes; (void)n_in; (void)out_size; (void)ws_size;
    const float* u          = (const float*)d_in[0];
    const float* log_dt     = (const float*)d_in[1];
    const float* log_A_real = (const float*)d_in[2];
    const float* A_imag     = (const float*)d_in[3];
    const float* C          = (const float*)d_in[4];
    const float* D          = (const float*)d_in[5];
    const float* W          = (const float*)d_in[6];
    const float* bias       = (const float*)d_in[7];
    float* out = (float*)d_out;
    float* ws  = (float*)d_ws;
    ushort* Wp  = (ushort*)(ws + OF_WP);
    ushort* gbf = (ushort*)(ws + OF_G);

    hipLaunchKernelGGL(k_consts, dim3(cHN / 256), dim3(256), 0, stream,
                       log_dt, log_A_real, A_imag, C, ws);
    hipLaunchKernelGGL(k_pack_w, dim3(1024 * 512 / 4 / 256), dim3(256), 0, stream, W, Wp);
    hipLaunchKernelGGL(k_chunk_state, dim3(cB * cH * cG / 256), dim3(256), 0, stream, u, ws);
    hipLaunchKernelGGL(k_scan, dim3(cB * cH * cN / 256), dim3(256), 0, stream, ws);
    hipLaunchKernelGGL(k_recur, dim3(cB * cH * cG / 256), dim3(256), 0, stream, u, D, ws);
    hipLaunchKernelGGL(k_gemm_mfma, dim3(cL / 128, 1024 / 128, cB), dim3(256), 0, stream,
                       Wp, bias, gbf, out);
}

// Round 3
// 330.443 us; speedup vs baseline: 2.0107x; 1.0556x over previous
//
#include <hip/hip_runtime.h>
#include <math.h>

// Problem dims (fixed by reference)
constexpr int cB = 8, cH = 512, cL = 4096, cN = 32;
constexpr int cG = 32, cLC = 128;            // 32 chunks of 128 along L
constexpr int cHN = cH * cN;                 // 16384

// Workspace layout (float offsets)
constexpr size_t OF_RR  = 0;                 // r real            [HN]
constexpr size_t OF_RI  = (size_t)cHN;       // r imag            [HN]
constexpr size_t OF_RPR = (size_t)2*cHN;     // r^128 real        [HN]
constexpr size_t OF_RPI = (size_t)3*cHN;     // r^128 imag        [HN]
constexpr size_t OF_C2R = (size_t)4*cHN;     // 2*Cs real         [HN]
constexpr size_t OF_C2I = (size_t)5*cHN;     // 2*Cs imag         [HN]
constexpr size_t OF_S   = (size_t)6*cHN;     // chunk states/inits: B*H*G*N complex
constexpr size_t OF_WP  = OF_S + (size_t)cB*cH*cG*cN*2;   // packed bf16 W: 1024*512 ushort
constexpr size_t OF_G   = OF_WP + (size_t)1024*512/2;     // bf16 g: B*H*L ushort

typedef __bf16 bf16x8 __attribute__((ext_vector_type(8)));
typedef float  f32x4  __attribute__((ext_vector_type(4)));

static __device__ __forceinline__ ushort f2bf(float x) {
    unsigned u = __float_as_uint(x);
    unsigned r = (u + 0x7fffu + ((u >> 16) & 1u)) >> 16;   // RNE
    return (ushort)r;
}

// ---------------- K0: per-(h,n) constants ----------------
__global__ void k_consts(const float* __restrict__ log_dt,
                         const float* __restrict__ log_A_real,
                         const float* __restrict__ A_imag,
                         const float* __restrict__ Cin,
                         float* __restrict__ ws)
{
    int tid = blockIdx.x * 256 + threadIdx.x;
    if (tid >= cHN) return;
    int h = tid >> 5;
    float dt = expf(log_dt[h]);
    float Ar = -expf(log_A_real[tid]);
    float Ai = A_imag[tid];
    float dr = dt * Ar, di = dt * Ai;
    float er = expf(dr);
    float rr = er * cosf(di), ri = er * sinf(di);
    float erL = expf(dr * (float)cLC);
    float diL = di * (float)cLC;
    float rpr = erL * cosf(diL), rpi = erL * sinf(diL);
    float cr = Cin[2*tid], ci = Cin[2*tid+1];
    float nr = rr - 1.0f, ni = ri;
    float inv = 1.0f / (Ar*Ar + Ai*Ai);
    float wr = (nr*Ar + ni*Ai) * inv;
    float wi = (ni*Ar - nr*Ai) * inv;
    float csr = cr*wr - ci*wi;
    float csi = cr*wi + ci*wr;
    ws[OF_RR  + tid] = rr;  ws[OF_RI  + tid] = ri;
    ws[OF_RPR + tid] = rpr; ws[OF_RPI + tid] = rpi;
    ws[OF_C2R + tid] = 2.0f*csr; ws[OF_C2I + tid] = 2.0f*csi;
}

// ---------------- K0b: pack W (fp32 [1024][512]) -> bf16 with GLU row interleave ----------------
__global__ void k_pack_w(const float* __restrict__ W, ushort* __restrict__ Wp)
{
    int idx = blockIdx.x * 256 + threadIdx.x;
    int base = idx * 4;
    int m = base >> 9;
    int k = base & 511;
    int src = (m & 1) ? (512 + (m >> 1)) : (m >> 1);
    float4 v = *(const float4*)&W[(size_t)src * 512 + k];
    ushort4 o;
    o.x = f2bf(v.x); o.y = f2bf(v.y); o.z = f2bf(v.z); o.w = f2bf(v.w);
    *(ushort4*)&Wp[base] = o;
}

// ---------------- K1: chunk states, n split across lane pairs (16 modes/thread) ----------------
__global__ __launch_bounds__(256) void k_chunk_state(const float* __restrict__ u,
                                                     float* __restrict__ ws)
{
    int gid = blockIdx.x * 256 + threadIdx.x;   // 2*B*H*G = 262144 threads
    int sub = gid & 1;
    int grp = gid >> 1;                          // = bh*32 + c
    int c  = grp & (cG - 1);
    int bh = grp >> 5;
    int h  = bh & (cH - 1);
    float rrv[16], riv[16];
    const float* crr = ws + OF_RR + (size_t)h * cN + 16*sub;
    const float* cri = ws + OF_RI + (size_t)h * cN + 16*sub;
    #pragma unroll
    for (int n = 0; n < 16; ++n) { rrv[n] = crr[n]; riv[n] = cri[n]; }
    float xr[16], xi[16];
    #pragma unroll
    for (int n = 0; n < 16; ++n) { xr[n] = 0.f; xi[n] = 0.f; }
    const float* up = u + (size_t)bh * cL + (size_t)c * cLC;
    for (int i0 = 0; i0 < cLC; i0 += 4) {
        float4 uv = *(const float4*)&up[i0];
        float us[4] = {uv.x, uv.y, uv.z, uv.w};
        #pragma unroll
        for (int s = 0; s < 4; ++s) {
            float uu = us[s];
            #pragma unroll
            for (int n = 0; n < 16; ++n) {
                float nxr = fmaf(rrv[n], xr[n], fmaf(-riv[n], xi[n], uu));
                float nxi = fmaf(rrv[n], xi[n], riv[n] * xr[n]);
                xr[n] = nxr; xi[n] = nxi;
            }
        }
    }
    // store this half's 16 complex states
    float* sp = ws + OF_S + (size_t)grp * (cN * 2) + 32*sub;
    #pragma unroll
    for (int q = 0; q < 8; ++q) {
        float4 v = make_float4(xr[2*q], xi[2*q], xr[2*q+1], xi[2*q+1]);
        *(float4*)&sp[4*q] = v;
    }
}

// ---------------- K2: scan across chunks, in-place s -> per-chunk init state ----------------
__global__ __launch_bounds__(256) void k_scan(float* __restrict__ ws)
{
    int tid = blockIdx.x * 256 + threadIdx.x;   // B*H*N = 131072 threads
    int n  = tid & (cN - 1);
    int bh = tid >> 5;
    int h  = bh & (cH - 1);
    float rpr = ws[OF_RPR + (size_t)h * cN + n];
    float rpi = ws[OF_RPI + (size_t)h * cN + n];
    float Xr = 0.f, Xi = 0.f;
    float* sp = ws + OF_S + ((size_t)bh * cG * cN + n) * 2;
    for (int c = 0; c < cG; ++c) {
        size_t idx = (size_t)c * cN * 2;
        float sr = sp[idx], si = sp[idx + 1];
        sp[idx] = Xr; sp[idx + 1] = Xi;
        float nXr = fmaf(rpr, Xr, fmaf(-rpi, Xi, sr));
        float nXi = fmaf(rpr, Xi, fmaf(rpi, Xr, si));
        Xr = nXr; Xi = nXi;
    }
}

// ---------------- K3: recurrence with init + y + D-skip + exact GELU -> g (bf16) ----------------
// n split across lane pairs; per-step y combined via shfl_xor(1); lanes split gelu by step parity.
__global__ __launch_bounds__(256) void k_recur(const float* __restrict__ u,
                                               const float* __restrict__ Dvec,
                                               float* __restrict__ ws)
{
    int gid = blockIdx.x * 256 + threadIdx.x;   // 2*B*H*G threads
    int sub = gid & 1;
    int grp = gid >> 1;
    int c  = grp & (cG - 1);
    int bh = grp >> 5;
    int h  = bh & (cH - 1);
    float rrv[16], riv[16], c2r[16], c2i[16];
    {
        const float* p0 = ws + OF_RR  + (size_t)h * cN + 16*sub;
        const float* p1 = ws + OF_RI  + (size_t)h * cN + 16*sub;
        const float* p2 = ws + OF_C2R + (size_t)h * cN + 16*sub;
        const float* p3 = ws + OF_C2I + (size_t)h * cN + 16*sub;
        #pragma unroll
        for (int n = 0; n < 16; ++n) { rrv[n]=p0[n]; riv[n]=p1[n]; c2r[n]=p2[n]; c2i[n]=p3[n]; }
    }
    float xr[16], xi[16];
    const float* ip = ws + OF_S + (size_t)grp * (cN * 2) + 32*sub;
    #pragma unroll
    for (int q = 0; q < 8; ++q) {
        float4 v = *(const float4*)&ip[4*q];
        xr[2*q] = v.x; xi[2*q] = v.y; xr[2*q+1] = v.z; xi[2*q+1] = v.w;
    }
    float Dh = Dvec[h];
    const float* up = u + (size_t)bh * cL + (size_t)c * cLC;
    ushort* gp = (ushort*)(ws + OF_G) + (size_t)bh * cL + (size_t)c * cLC;

    auto stepv = [&](float uu) -> float {
        float part = 0.f;
        #pragma unroll
        for (int n = 0; n < 16; ++n) {
            float nxr = fmaf(rrv[n], xr[n], fmaf(-riv[n], xi[n], uu));
            float nxi = fmaf(rrv[n], xi[n], riv[n] * xr[n]);
            xr[n] = nxr; xi[n] = nxi;
            part = fmaf(c2r[n], nxr, part);
            part = fmaf(-c2i[n], nxi, part);
        }
        float full = part + __shfl_xor(part, 1, 64);
        return fmaf(uu, Dh, full);
    };

    for (int i0 = 0; i0 < cLC; i0 += 4) {
        float4 uv = *(const float4*)&up[i0];
        float v0 = stepv(uv.x);
        float v1 = stepv(uv.y);
        float v2 = stepv(uv.z);
        float v3 = stepv(uv.w);
        // lane 0 handles steps 0,1; lane 1 handles steps 2,3
        float a = sub ? v2 : v0;
        float b = sub ? v3 : v1;
        float ga = 0.5f * a * (1.0f + erff(a * 0.70710678118654752f));
        float gb = 0.5f * b * (1.0f + erff(b * 0.70710678118654752f));
        ushort2 st; st.x = f2bf(ga); st.y = f2bf(gb);
        *(ushort2*)&gp[i0 + 2*sub] = st;
    }
}

// ---------------- K4: MFMA GEMM + bias + GLU ----------------
constexpr int BK = 32, LDK = 40;   // LDS row stride (bf16): 80B = 20 banks, 2-way-free b128
__global__ __launch_bounds__(256) void k_gemm_mfma(const ushort* __restrict__ Wp,
                                                   const float* __restrict__ bias,
                                                   const ushort* __restrict__ gbf,
                                                   float* __restrict__ out)
{
    __shared__ ushort As[128 * LDK];
    __shared__ ushort Bs[128 * LDK];
    const int t    = threadIdx.x;
    const int l0   = blockIdx.x * 128;
    const int by   = blockIdx.y;
    const int b    = blockIdx.z;
    const int wave = t >> 6, lane = t & 63;
    const int wm   = wave & 1, wn = wave >> 1;
    const int lm   = lane & 15, q = lane >> 4;

    const int arow = t & 127;
    const int ah   = t >> 7;
    const int lq = t & 15, kp = t >> 4;
    const int ko = kp >> 2;
    const int kr = (2 * kp) & 7;

    const ushort* gB = gbf + (size_t)b * ((size_t)cH * cL);
    const ushort* wRow = Wp + (size_t)(by * 128 + arow) * 512 + ah * 16;

    f32x4 acc[4][4];
    #pragma unroll
    for (int i = 0; i < 4; ++i)
        #pragma unroll
        for (int j = 0; j < 4; ++j)
            acc[i][j] = (f32x4){0.f, 0.f, 0.f, 0.f};

    for (int k0 = 0; k0 < cH; k0 += BK) {
        uint4 wa0 = *(const uint4*)&wRow[k0];
        uint4 wa1 = *(const uint4*)&wRow[k0 + 8];
        uint4 g0  = *(const uint4*)&gB[(size_t)(k0 + 2*kp)     * cL + l0 + 8*lq];
        uint4 g1  = *(const uint4*)&gB[(size_t)(k0 + 2*kp + 1) * cL + l0 + 8*lq];
        __syncthreads();
        *(uint4*)&As[arow * LDK + 16*ah]     = wa0;
        *(uint4*)&As[arow * LDK + 16*ah + 8] = wa1;
        {
            unsigned ua[4] = {g0.x, g0.y, g0.z, g0.w};
            unsigned ub[4] = {g1.x, g1.y, g1.z, g1.w};
            #pragma unroll
            for (int e = 0; e < 4; ++e) {
                unsigned w0 = (ua[e] & 0xffffu) | (ub[e] << 16);
                unsigned w1 = (ua[e] >> 16)     | (ub[e] & 0xffff0000u);
                int lr0 = 8*lq + 2*e;
                int c0  = ((ko ^ (lq & 3)) << 3) + kr;
                *(unsigned*)&Bs[lr0 * LDK + c0]       = w0;
                *(unsigned*)&Bs[(lr0 + 1) * LDK + c0] = w1;
            }
        }
        __syncthreads();
        bf16x8 af[4], bf[4];
        #pragma unroll
        for (int mi = 0; mi < 4; ++mi) {
            int row = 64*wm + 16*mi + lm;
            af[mi] = *(const bf16x8*)&As[row * LDK + (q << 3)];
        }
        #pragma unroll
        for (int ni = 0; ni < 4; ++ni) {
            int row = 64*wn + 16*ni + lm;
            int kx  = (row >> 3) & 3;
            bf[ni] = *(const bf16x8*)&Bs[row * LDK + ((q ^ kx) << 3)];
        }
        #pragma unroll
        for (int mi = 0; mi < 4; ++mi)
            #pragma unroll
            for (int ni = 0; ni < 4; ++ni)
                acc[mi][ni] = __builtin_amdgcn_mfma_f32_16x16x32_bf16(af[mi], bf[ni], acc[mi][ni], 0, 0, 0);
    }

    const int obase = by * 64 + 32 * wm;
    #pragma unroll
    for (int mi = 0; mi < 4; ++mi) {
        #pragma unroll
        for (int p = 0; p < 2; ++p) {
            int o = obase + 8*mi + 2*q + p;
            float ba = bias[o], bb = bias[512 + o];
            float* orow = out + ((size_t)b * cH + o) * cL + l0 + 64*wn + lm;
            #pragma unroll
            for (int ni = 0; ni < 4; ++ni) {
                float av = acc[mi][ni][2*p]     + ba;
                float gv = acc[mi][ni][2*p + 1] + bb;
                orow[16 * ni] = av / (1.f + expf(-gv));
            }
        }
    }
}

extern "C" void kernel_launch(void* const* d_in, const int* in_sizes, int n_in,
                              void* d_out, int out_size, void* d_ws, size_t ws_size,
                              hipStream_t stream)
{
    (void)in_sizes; (void)n_in; (void)out_size; (void)ws_size;
    const float* u          = (const float*)d_in[0];
    const float* log_dt     = (const float*)d_in[1];
    const float* log_A_real = (const float*)d_in[2];
    const float* A_imag     = (const float*)d_in[3];
    const float* C          = (const float*)d_in[4];
    const float* D          = (const float*)d_in[5];
    const float* W          = (const float*)d_in[6];
    const float* bias       = (const float*)d_in[7];
    float* out = (float*)d_out;
    float* ws  = (float*)d_ws;
    ushort* Wp  = (ushort*)(ws + OF_WP);
    ushort* gbf = (ushort*)(ws + OF_G);

    hipLaunchKernelGGL(k_consts, dim3(cHN / 256), dim3(256), 0, stream,
                       log_dt, log_A_real, A_imag, C, ws);
    hipLaunchKernelGGL(k_pack_w, dim3(1024 * 512 / 4 / 256), dim3(256), 0, stream, W, Wp);
    hipLaunchKernelGGL(k_chunk_state, dim3(2 * cB * cH * cG / 256), dim3(256), 0, stream, u, ws);
    hipLaunchKernelGGL(k_scan, dim3(cB * cH * cN / 256), dim3(256), 0, stream, ws);
    hipLaunchKernelGGL(k_recur, dim3(2 * cB * cH * cG / 256), dim3(256), 0, stream, u, D, ws);
    hipLaunchKernelGGL(k_gemm_mfma, dim3(cL / 128, 1024 / 128, cB), dim3(256), 0, stream,
                       Wp, bias, gbf, out);
}

// Round 4
// 296.242 us; speedup vs baseline: 2.2429x; 1.1154x over previous
//
#include <hip/hip_runtime.h>
#include <math.h>

// Problem dims (fixed by reference)
constexpr int cB = 8, cH = 512, cL = 4096, cN = 32;
constexpr int cG = 32, cLC = 128;            // 32 chunks of 128 along L
constexpr int cHN = cH * cN;                 // 16384

// Workspace layout (float offsets)
constexpr size_t OF_RR  = 0;
constexpr size_t OF_RI  = (size_t)cHN;
constexpr size_t OF_RPR = (size_t)2*cHN;     // r^128
constexpr size_t OF_RPI = (size_t)3*cHN;
constexpr size_t OF_C2R = (size_t)4*cHN;     // 2*Cs
constexpr size_t OF_C2I = (size_t)5*cHN;
constexpr size_t OF_DR  = (size_t)6*cHN;     // dt*Ar
constexpr size_t OF_DI  = (size_t)7*cHN;     // dt*Ai
constexpr size_t OF_K   = (size_t)8*cHN;                  // k_h[d] fp32 [512][128]
constexpr size_t OF_WP  = OF_K + (size_t)512*128;         // bf16 W packed: 1024*512 ush
constexpr size_t OF_A   = OF_WP + (size_t)1024*512/2;     // bf16 A=[T|Er|-Ei]: [512][128][192] ush
constexpr size_t OF_V   = OF_A + (size_t)512*128*192/2;   // bf16 V: [512][64][128] ush
constexpr size_t OF_XP  = OF_V + (size_t)512*64*128/2;    // bf16 states: [512][256][64] ush
constexpr size_t OF_G   = OF_XP + (size_t)512*256*64/2;   // bf16 g: [B][H][L] ush
// end = OF_G + 8388608 = 21,430,272 floats = 85.7 MB

typedef __bf16 bf16x8 __attribute__((ext_vector_type(8)));
typedef float  f32x4  __attribute__((ext_vector_type(4)));

static __device__ __forceinline__ ushort f2bf(float x) {
    unsigned u = __float_as_uint(x);
    unsigned r = (u + 0x7fffu + ((u >> 16) & 1u)) >> 16;   // RNE
    return (ushort)r;
}
static __device__ __forceinline__ float bf2f(ushort v) {
    return __uint_as_float(((unsigned)v) << 16);
}
static __device__ __forceinline__ unsigned pk2(float a, float b) {
    return (unsigned)f2bf(a) | ((unsigned)f2bf(b) << 16);
}
static __device__ __forceinline__ float gelu(float v) {
    return 0.5f * v * (1.0f + erff(v * 0.70710678118654752f));
}

// ---------------- K0: per-(h,n) constants ----------------
__global__ void k_consts(const float* __restrict__ log_dt,
                         const float* __restrict__ log_A_real,
                         const float* __restrict__ A_imag,
                         const float* __restrict__ Cin,
                         float* __restrict__ ws)
{
    int tid = blockIdx.x * 256 + threadIdx.x;
    if (tid >= cHN) return;
    int h = tid >> 5;
    float dt = expf(log_dt[h]);
    float Ar = -expf(log_A_real[tid]);
    float Ai = A_imag[tid];
    float dr = dt * Ar, di = dt * Ai;
    float er = expf(dr);
    float rr = er * cosf(di), ri = er * sinf(di);
    float erL = expf(dr * (float)cLC);
    float diL = di * (float)cLC;
    float rpr = erL * cosf(diL), rpi = erL * sinf(diL);
    float cr = Cin[2*tid], ci = Cin[2*tid+1];
    float nr = rr - 1.0f, ni = ri;
    float inv = 1.0f / (Ar*Ar + Ai*Ai);
    float wr = (nr*Ar + ni*Ai) * inv;
    float wi = (ni*Ar - nr*Ai) * inv;
    float csr = cr*wr - ci*wi;
    float csi = cr*wi + ci*wr;
    ws[OF_RR  + tid] = rr;  ws[OF_RI  + tid] = ri;
    ws[OF_RPR + tid] = rpr; ws[OF_RPI + tid] = rpi;
    ws[OF_C2R + tid] = 2.0f*csr; ws[OF_C2I + tid] = 2.0f*csi;
    ws[OF_DR  + tid] = dr;  ws[OF_DI  + tid] = di;
}

// ---------------- K0b: pack W -> bf16 with GLU row interleave ----------------
__global__ void k_pack_w(const float* __restrict__ W, ushort* __restrict__ Wp)
{
    int idx = blockIdx.x * 256 + threadIdx.x;
    int base = idx * 4;
    int m = base >> 9;
    int k = base & 511;
    int src = (m & 1) ? (512 + (m >> 1)) : (m >> 1);
    float4 v = *(const float4*)&W[(size_t)src * 512 + k];
    ushort4 o;
    o.x = f2bf(v.x); o.y = f2bf(v.y); o.z = f2bf(v.z); o.w = f2bf(v.w);
    *(ushort4*)&Wp[base] = o;
}

// ---------------- V matrix: V[h][n][j]=Re(r^(127-j)), [h][32+n][j]=Im ----------------
__global__ void k_vmat(const float* __restrict__ ws, ushort* __restrict__ wsu)
{
    int tid = blockIdx.x * 256 + threadIdx.x;   // 16384
    int h = tid >> 5, n = tid & 31;
    float dr = ws[OF_DR + tid], di = ws[OF_DI + tid];
    float e127 = expf(dr * 127.f), a127 = di * 127.f;
    float pr = e127 * cosf(a127), pi_ = e127 * sinf(a127);
    float rie = expf(-dr);
    float rc = rie * cosf(di), rs = -rie * sinf(di);
    ushort* vre = wsu + 2*OF_V + ((size_t)h*64 + n) * 128;
    ushort* vim = wsu + 2*OF_V + ((size_t)h*64 + 32 + n) * 128;
    for (int j4 = 0; j4 < 128; j4 += 4) {
        ushort4 r4, i4;
        #pragma unroll
        for (int e = 0; e < 4; ++e) {
            ((ushort*)&r4)[e] = f2bf(pr);
            ((ushort*)&i4)[e] = f2bf(pi_);
            float npr = pr*rc - pi_*rs;
            float npi = pr*rs + pi_*rc;
            pr = npr; pi_ = npi;
        }
        *(ushort4*)&vre[j4] = r4;
        *(ushort4*)&vim[j4] = i4;
    }
}

// ---------------- E matrix + k vector: per (h,l) ----------------
__global__ void k_emat(const float* __restrict__ ws, float* __restrict__ wsf,
                       ushort* __restrict__ wsu)
{
    int tid = blockIdx.x * 256 + threadIdx.x;   // 65536
    int h = tid >> 7, l = tid & 127;
    float fl = (float)l, fl1 = (float)(l + 1);
    const float* dr_ = ws + OF_DR + (size_t)h*32;
    const float* di_ = ws + OF_DI + (size_t)h*32;
    const float* c2r_ = ws + OF_C2R + (size_t)h*32;
    const float* c2i_ = ws + OF_C2I + (size_t)h*32;
    ushort* rowA = wsu + 2*OF_A + ((size_t)h*128 + l) * 192;
    float kacc = 0.f;
    for (int n4 = 0; n4 < 32; n4 += 4) {
        ushort4 prq, npq;
        #pragma unroll
        for (int e = 0; e < 4; ++e) {
            int n = n4 + e;
            float dr = dr_[n], di = di_[n], c2r = c2r_[n], c2i = c2i_[n];
            float e0 = expf(dr * fl), a0 = di * fl;
            float c0 = cosf(a0), s0 = sinf(a0);
            kacc += e0 * (c2r*c0 - c2i*s0);
            float e1 = expf(dr * fl1), a1 = di * fl1;
            float c1 = cosf(a1), s1 = sinf(a1);
            ((ushort*)&prq)[e] = f2bf(e1 * (c2r*c1 - c2i*s1));
            ((ushort*)&npq)[e] = f2bf(-e1 * (c2r*s1 + c2i*c1));
        }
        *(ushort4*)&rowA[128 + n4] = prq;
        *(ushort4*)&rowA[160 + n4] = npq;
    }
    wsf[OF_K + (size_t)h*128 + l] = kacc;
}

// ---------------- Toeplitz fill: A[h][l][j] = k[l-j] (j<=l), diag += D ----------------
__global__ void k_build_T(const float* __restrict__ wsf, const float* __restrict__ Dvec,
                          ushort* __restrict__ wsu)
{
    __shared__ float kv[256];
    int t = threadIdx.x;
    int tid = blockIdx.x * 256 + t;             // 65536
    int h = tid >> 7, l = tid & 127;
    kv[t] = wsf[OF_K + (size_t)blockIdx.x * 256 + t];
    __syncthreads();
    const float* krow = kv + ((t >> 7) << 7);
    float Dh = Dvec[h];
    ushort* row = wsu + 2*OF_A + ((size_t)h*128 + l) * 192;
    for (int j8 = 0; j8 < 128; j8 += 8) {
        uint4 q;
        unsigned w[4];
        #pragma unroll
        for (int p = 0; p < 4; ++p) {
            int j0 = j8 + 2*p, j1 = j0 + 1;
            float v0 = (j0 <= l) ? krow[l - j0] : 0.f;
            float v1 = (j1 <= l) ? krow[l - j1] : 0.f;
            if (j0 == l) v0 += Dh;
            if (j1 == l) v1 += Dh;
            w[p] = pk2(v0, v1);
        }
        q.x = w[0]; q.y = w[1]; q.z = w[2]; q.w = w[3];
        *(uint4*)&row[j8] = q;
    }
}

// ---------------- State GEMM: per h, Xp[h][col][comp] = sum_j V[comp][j] * u[col][j] ----------------
__global__ __launch_bounds__(256) void k_state_gemm(const float* __restrict__ u,
                                                    const ushort* __restrict__ wsu,
                                                    ushort* __restrict__ xp)
{
    __shared__ ushort Vs[64 * 136];
    __shared__ ushort Bs[256 * 40];
    const int t = threadIdx.x;
    const int h = blockIdx.x;
    const int wn = t >> 6, lane = t & 63;
    const int lm = lane & 15, q = lane >> 4;

    {   // stage V[h] whole: 64x128 bf16
        int idx = t * 32;
        int row = idx >> 7, kk = idx & 127;
        const ushort* src = wsu + 2*OF_V + ((size_t)h*64 + row) * 128 + kk;
        uint4 v0 = *(const uint4*)&src[0],  v1 = *(const uint4*)&src[8];
        uint4 v2 = *(const uint4*)&src[16], v3 = *(const uint4*)&src[24];
        ushort* d = (ushort*)Vs + row * 136 + kk;
        *(uint4*)&d[0] = v0; *(uint4*)&d[8] = v1;
        *(uint4*)&d[16] = v2; *(uint4*)&d[24] = v3;
    }

    const int b = t >> 5, c = t & 31;
    f32x4 acc[4][4];
    #pragma unroll
    for (int i = 0; i < 4; ++i)
        #pragma unroll
        for (int j = 0; j < 4; ++j) acc[i][j] = (f32x4){0.f,0.f,0.f,0.f};

    for (int k0 = 0; k0 < 128; k0 += 32) {
        const float* up = u + ((size_t)(b*cH + h)) * cL + (size_t)c*128 + k0;
        float4 f[8];
        #pragma unroll
        for (int e = 0; e < 8; ++e) f[e] = *(const float4*)&up[4*e];
        __syncthreads();
        ushort* d = (ushort*)Bs + t * 40;
        #pragma unroll
        for (int e = 0; e < 4; ++e) {
            uint4 w;
            w.x = pk2(f[2*e].x, f[2*e].y);   w.y = pk2(f[2*e].z, f[2*e].w);
            w.z = pk2(f[2*e+1].x, f[2*e+1].y); w.w = pk2(f[2*e+1].z, f[2*e+1].w);
            *(uint4*)&d[8*e] = w;
        }
        __syncthreads();
        bf16x8 af[4], bfr[4];
        #pragma unroll
        for (int mi = 0; mi < 4; ++mi)
            af[mi] = *(const bf16x8*)&Vs[(16*mi + lm) * 136 + k0 + 8*q];
        #pragma unroll
        for (int ni = 0; ni < 4; ++ni)
            bfr[ni] = *(const bf16x8*)&Bs[(64*wn + 16*ni + lm) * 40 + 8*q];
        #pragma unroll
        for (int mi = 0; mi < 4; ++mi)
            #pragma unroll
            for (int ni = 0; ni < 4; ++ni)
                acc[mi][ni] = __builtin_amdgcn_mfma_f32_16x16x32_bf16(af[mi], bfr[ni], acc[mi][ni], 0,0,0);
    }
    // write: comp = 16mi+4q+i, col = 64wn+16ni+lm
    #pragma unroll
    for (int mi = 0; mi < 4; ++mi)
        #pragma unroll
        for (int ni = 0; ni < 4; ++ni) {
            int col = 64*wn + 16*ni + lm;
            int comp = 16*mi + 4*q;
            ushort4 st;
            st.x = f2bf(acc[mi][ni][0]); st.y = f2bf(acc[mi][ni][1]);
            st.z = f2bf(acc[mi][ni][2]); st.w = f2bf(acc[mi][ni][3]);
            *(ushort4*)&xp[((size_t)h*256 + col) * 64 + comp] = st;
        }
}

// ---------------- Scan: in-place Xp chunk-sums -> init states ----------------
__global__ __launch_bounds__(256) void k_scan2(const float* __restrict__ ws,
                                               ushort* __restrict__ xp)
{
    int tid = blockIdx.x * 256 + threadIdx.x;   // B*H*N = 131072
    int n  = tid & 31;
    int bh = tid >> 5;
    int h  = bh & (cH - 1);
    int b  = bh >> 9;
    float rpr = ws[OF_RPR + (size_t)h*32 + n];
    float rpi = ws[OF_RPI + (size_t)h*32 + n];
    float Xr = 0.f, Xi = 0.f;
    ushort* base = xp + ((size_t)h*256 + (size_t)b*32) * 64 + n;
    for (int c = 0; c < cG; ++c) {
        ushort* p = base + (size_t)c * 64;
        float sr = bf2f(p[0]), si = bf2f(p[32]);
        p[0]  = f2bf(Xr);
        p[32] = f2bf(Xi);
        float nXr = fmaf(rpr, Xr, fmaf(-rpi, Xi, sr));
        float nXi = fmaf(rpr, Xi, fmaf(rpi, Xr, si));
        Xr = nXr; Xi = nXi;
    }
}

// ---------------- Conv GEMM: per (h, coltile): g = gelu(A[128x192] * [u;xr;xi]) ----------------
__global__ __launch_bounds__(256) void k_conv(const float* __restrict__ u,
                                              const ushort* __restrict__ wsu,
                                              ushort* __restrict__ g)
{
    __shared__ ushort As[128 * 40];
    __shared__ ushort Bs[128 * 40];
    const int t = threadIdx.x;
    const int ctile = blockIdx.x;     // 0..1
    const int h = blockIdx.y;
    const int wave = t >> 6, lane = t & 63;
    const int wm = wave & 1, wn = wave >> 1;
    const int lm = lane & 15, q = lane >> 4;

    const int arow = t & 127, ah = t >> 7;
    const int col = arow, half = ah;
    const int gc = ctile * 128 + col;
    const int ub = gc >> 5, uc = gc & 31;

    const ushort* Ab = wsu + 2*OF_A + ((size_t)h*128 + arow) * 192;
    const ushort* xpB = wsu + 2*OF_XP + ((size_t)h*256 + gc) * 64;

    f32x4 acc[4][4];
    #pragma unroll
    for (int i = 0; i < 4; ++i)
        #pragma unroll
        for (int j = 0; j < 4; ++j) acc[i][j] = (f32x4){0.f,0.f,0.f,0.f};

    for (int k0 = 0; k0 < 192; k0 += 32) {
        uint4 a0 = *(const uint4*)&Ab[k0 + 16*ah];
        uint4 a1 = *(const uint4*)&Ab[k0 + 16*ah + 8];
        uint4 b0, b1;
        if (k0 < 128) {
            const float* up = u + ((size_t)(ub*cH + h)) * cL + (size_t)uc*128 + k0 + 16*half;
            float4 f0 = *(const float4*)&up[0],  f1 = *(const float4*)&up[4];
            float4 f2 = *(const float4*)&up[8],  f3 = *(const float4*)&up[12];
            b0.x = pk2(f0.x,f0.y); b0.y = pk2(f0.z,f0.w);
            b0.z = pk2(f1.x,f1.y); b0.w = pk2(f1.z,f1.w);
            b1.x = pk2(f2.x,f2.y); b1.y = pk2(f2.z,f2.w);
            b1.z = pk2(f3.x,f3.y); b1.w = pk2(f3.z,f3.w);
        } else {
            const ushort* xs = xpB + (k0 - 128) + 16*half;
            b0 = *(const uint4*)&xs[0];
            b1 = *(const uint4*)&xs[8];
        }
        __syncthreads();
        *(uint4*)&As[arow*40 + 16*ah]     = a0;
        *(uint4*)&As[arow*40 + 16*ah + 8] = a1;
        *(uint4*)&Bs[col*40 + 16*half]     = b0;
        *(uint4*)&Bs[col*40 + 16*half + 8] = b1;
        __syncthreads();
        // lower-triangular skip: rows 0..63 x k 64..127 are all zero
        bool skip = (wm == 0) && (k0 == 64 || k0 == 96);
        if (!skip) {
            bf16x8 af[4], bfr[4];
            #pragma unroll
            for (int mi = 0; mi < 4; ++mi)
                af[mi] = *(const bf16x8*)&As[(64*wm + 16*mi + lm) * 40 + 8*q];
            #pragma unroll
            for (int ni = 0; ni < 4; ++ni)
                bfr[ni] = *(const bf16x8*)&Bs[(64*wn + 16*ni + lm) * 40 + 8*q];
            #pragma unroll
            for (int mi = 0; mi < 4; ++mi)
                #pragma unroll
                for (int ni = 0; ni < 4; ++ni)
                    acc[mi][ni] = __builtin_amdgcn_mfma_f32_16x16x32_bf16(af[mi], bfr[ni], acc[mi][ni], 0,0,0);
        }
    }
    // epilogue: gelu -> bf16 g[b][h][c*128 + l]
    #pragma unroll
    for (int ni = 0; ni < 4; ++ni) {
        int ocol = ctile*128 + 64*wn + 16*ni + lm;
        int ob = ocol >> 5, oc = ocol & 31;
        ushort* grow = g + ((size_t)(ob*cH + h)) * cL + (size_t)oc*128;
        #pragma unroll
        for (int mi = 0; mi < 4; ++mi) {
            int l = 64*wm + 16*mi + 4*q;
            ushort4 st;
            st.x = f2bf(gelu(acc[mi][ni][0]));
            st.y = f2bf(gelu(acc[mi][ni][1]));
            st.z = f2bf(gelu(acc[mi][ni][2]));
            st.w = f2bf(gelu(acc[mi][ni][3]));
            *(ushort4*)&grow[l] = st;
        }
    }
}

// ---------------- K4: big MFMA GEMM + bias + GLU (unchanged) ----------------
constexpr int LDK = 40;
__global__ __launch_bounds__(256) void k_gemm_mfma(const ushort* __restrict__ Wp,
                                                   const float* __restrict__ bias,
                                                   const ushort* __restrict__ gbf,
                                                   float* __restrict__ out)
{
    __shared__ ushort As[128 * LDK];
    __shared__ ushort Bs[128 * LDK];
    const int t    = threadIdx.x;
    const int l0   = blockIdx.x * 128;
    const int by   = blockIdx.y;
    const int b    = blockIdx.z;
    const int wave = t >> 6, lane = t & 63;
    const int wm   = wave & 1, wn = wave >> 1;
    const int lm   = lane & 15, q = lane >> 4;

    const int arow = t & 127;
    const int ah   = t >> 7;
    const int lq = t & 15, kp = t >> 4;
    const int ko = kp >> 2;
    const int kr = (2 * kp) & 7;

    const ushort* gB = gbf + (size_t)b * ((size_t)cH * cL);
    const ushort* wRow = Wp + (size_t)(by * 128 + arow) * 512 + ah * 16;

    f32x4 acc[4][4];
    #pragma unroll
    for (int i = 0; i < 4; ++i)
        #pragma unroll
        for (int j = 0; j < 4; ++j)
            acc[i][j] = (f32x4){0.f, 0.f, 0.f, 0.f};

    for (int k0 = 0; k0 < cH; k0 += 32) {
        uint4 wa0 = *(const uint4*)&wRow[k0];
        uint4 wa1 = *(const uint4*)&wRow[k0 + 8];
        uint4 g0  = *(const uint4*)&gB[(size_t)(k0 + 2*kp)     * cL + l0 + 8*lq];
        uint4 g1  = *(const uint4*)&gB[(size_t)(k0 + 2*kp + 1) * cL + l0 + 8*lq];
        __syncthreads();
        *(uint4*)&As[arow * LDK + 16*ah]     = wa0;
        *(uint4*)&As[arow * LDK + 16*ah + 8] = wa1;
        {
            unsigned ua[4] = {g0.x, g0.y, g0.z, g0.w};
            unsigned ub[4] = {g1.x, g1.y, g1.z, g1.w};
            #pragma unroll
            for (int e = 0; e < 4; ++e) {
                unsigned w0 = (ua[e] & 0xffffu) | (ub[e] << 16);
                unsigned w1 = (ua[e] >> 16)     | (ub[e] & 0xffff0000u);
                int lr0 = 8*lq + 2*e;
                int c0  = ((ko ^ (lq & 3)) << 3) + kr;
                *(unsigned*)&Bs[lr0 * LDK + c0]       = w0;
                *(unsigned*)&Bs[(lr0 + 1) * LDK + c0] = w1;
            }
        }
        __syncthreads();
        bf16x8 af[4], bf[4];
        #pragma unroll
        for (int mi = 0; mi < 4; ++mi) {
            int row = 64*wm + 16*mi + lm;
            af[mi] = *(const bf16x8*)&As[row * LDK + (q << 3)];
        }
        #pragma unroll
        for (int ni = 0; ni < 4; ++ni) {
            int row = 64*wn + 16*ni + lm;
            int kx  = (row >> 3) & 3;
            bf[ni] = *(const bf16x8*)&Bs[row * LDK + ((q ^ kx) << 3)];
        }
        #pragma unroll
        for (int mi = 0; mi < 4; ++mi)
            #pragma unroll
            for (int ni = 0; ni < 4; ++ni)
                acc[mi][ni] = __builtin_amdgcn_mfma_f32_16x16x32_bf16(af[mi], bf[ni], acc[mi][ni], 0, 0, 0);
    }

    const int obase = by * 64 + 32 * wm;
    #pragma unroll
    for (int mi = 0; mi < 4; ++mi) {
        #pragma unroll
        for (int p = 0; p < 2; ++p) {
            int o = obase + 8*mi + 2*q + p;
            float ba = bias[o], bb = bias[512 + o];
            float* orow = out + ((size_t)b * cH + o) * cL + l0 + 64*wn + lm;
            #pragma unroll
            for (int ni = 0; ni < 4; ++ni) {
                float av = acc[mi][ni][2*p]     + ba;
                float gv = acc[mi][ni][2*p + 1] + bb;
                orow[16 * ni] = av / (1.f + expf(-gv));
            }
        }
    }
}

extern "C" void kernel_launch(void* const* d_in, const int* in_sizes, int n_in,
                              void* d_out, int out_size, void* d_ws, size_t ws_size,
                              hipStream_t stream)
{
    (void)in_sizes; (void)n_in; (void)out_size; (void)ws_size;
    const float* u          = (const float*)d_in[0];
    const float* log_dt     = (const float*)d_in[1];
    const float* log_A_real = (const float*)d_in[2];
    const float* A_imag     = (const float*)d_in[3];
    const float* C          = (const float*)d_in[4];
    const float* D          = (const float*)d_in[5];
    const float* W          = (const float*)d_in[6];
    const float* bias       = (const float*)d_in[7];
    float* out = (float*)d_out;
    float* ws  = (float*)d_ws;
    ushort* wsu = (ushort*)d_ws;
    ushort* Wp  = wsu + 2*OF_WP;
    ushort* xp  = wsu + 2*OF_XP;
    ushort* gbf = wsu + 2*OF_G;

    hipLaunchKernelGGL(k_consts, dim3(cHN/256), dim3(256), 0, stream,
                       log_dt, log_A_real, A_imag, C, ws);
    hipLaunchKernelGGL(k_pack_w, dim3(1024*512/4/256), dim3(256), 0, stream, W, Wp);
    hipLaunchKernelGGL(k_vmat, dim3(cHN/256), dim3(256), 0, stream, ws, wsu);
    hipLaunchKernelGGL(k_emat, dim3(512*128/256), dim3(256), 0, stream, ws, ws, wsu);
    hipLaunchKernelGGL(k_build_T, dim3(512*128/256), dim3(256), 0, stream, ws, D, wsu);
    hipLaunchKernelGGL(k_state_gemm, dim3(512), dim3(256), 0, stream, u, wsu, xp);
    hipLaunchKernelGGL(k_scan2, dim3(cB*cH*cN/256), dim3(256), 0, stream, ws, xp);
    hipLaunchKernelGGL(k_conv, dim3(2, 512), dim3(256), 0, stream, u, wsu, gbf);
    hipLaunchKernelGGL(k_gemm_mfma, dim3(cL/128, 1024/128, cB), dim3(256), 0, stream,
                       Wp, bias, gbf, out);
}